// Round 9
// baseline (282.381 us; speedup 1.0000x reference)
//
#include <hip/hip_runtime.h>
#include <hip/hip_bf16.h>
#include <math.h>

// ---------- types ----------
typedef __attribute__((ext_vector_type(8))) short          short8;   // 8 bf16 (MFMA frag)
typedef __attribute__((ext_vector_type(8))) unsigned short u16x8;    // 16B chunk
typedef __attribute__((ext_vector_type(2))) unsigned int   u32x2;    // 8B chunk
typedef __attribute__((ext_vector_type(4))) float          f32x4;    // MFMA acc 16x16
typedef __attribute__((ext_vector_type(16))) float         f32x16;   // MFMA acc 32x32

#define MFMA_BF16(a, b, c) __builtin_amdgcn_mfma_f32_16x16x32_bf16((a), (b), (c), 0, 0, 0)
#define MFMA32(a, b, c)    __builtin_amdgcn_mfma_f32_32x32x16_bf16((a), (b), (c), 0, 0, 0)

// async global->LDS, 16B per lane; LDS dst = wave-uniform base + lane*16
#define GLOAD_LDS16(gp, lp)                                        \
  __builtin_amdgcn_global_load_lds(                                \
      (const __attribute__((address_space(1))) void*)(gp),         \
      (__attribute__((address_space(3))) void*)(lp), 16, 0, 0)

// B=1, HID=1024, NH=16, D=64, S=8192, TILE=128, NTILE=64, 12 kv tiles/q tile
// Inputs fp32, output fp32 (verified rounds 1/5).

__device__ __forceinline__ unsigned short f2bf(float f) {
  union { float f; unsigned int u; } v; v.f = f;
  unsigned int r = v.u + 0x7fffu + ((v.u >> 16) & 1u);   // RNE
  return (unsigned short)(r >> 16);
}
// pack two positive floats to a bf16 pair in ONE VALU op (a -> low 16, b -> high).
__device__ __forceinline__ unsigned int pack2bf(float a, float b) {
  unsigned int r;
  asm("v_cvt_pk_bf16_f32 %0, %1, %2" : "=v"(r) : "v"(a), "v"(b));
  return r;
}

// tile-order row r -> natural sequence index s
__device__ __forceinline__ int row_to_seq(int r) {
  int tile = r >> 7, pos = r & 127;
  int ntt = tile >> 4, nth = (tile >> 2) & 3, ntw = tile & 3;
  int tt  = pos >> 6,  th  = (pos >> 3) & 7,  tw  = pos & 7;
  return ((ntt * 2 + tt) << 10) | ((nth * 8 + th) << 5) | (ntw * 8 + tw);
}

// ---------- kernel 1: permute hidden_states rows into tile order (+cast fp32->bf16) ----------
__global__ __launch_bounds__(256) void permute_hs(const float* __restrict__ in,
                                                  unsigned short* __restrict__ out) {
  int cid = blockIdx.x * 256 + threadIdx.x;          // 1,048,576 chunks of 8 elems
  int r = cid >> 7, c = (cid & 127) * 8;
  int s = row_to_seq(r);
  const float* f = in + (size_t)s * 1024 + c;
  u16x8 v;
#pragma unroll
  for (int j = 0; j < 8; ++j) v[j] = f2bf(f[j]);
  *(u16x8*)(out + (size_t)r * 1024 + c) = v;
}

// ---------- kernel 2: transpose the 4 weight matrices [K][N] -> [N][K] (+cast) ----------
__global__ __launch_bounds__(256) void transpose_w(const float* __restrict__ w0,
                                                   const float* __restrict__ w1,
                                                   const float* __restrict__ w2,
                                                   const float* __restrict__ w3,
                                                   unsigned short* __restrict__ out) {
  __shared__ unsigned short Lt[64 * 68];             // [n][k] tile, pad 68
  int m = blockIdx.y;
  const float* W = (m == 0) ? w0 : (m == 1) ? w1 : (m == 2) ? w2 : w3;
  unsigned short* O = out + (size_t)m * 1048576;
  int k0 = (blockIdx.x >> 4) * 64, n0 = (blockIdx.x & 15) * 64;
  int tid = threadIdx.x;
#pragma unroll
  for (int i = 0; i < 2; ++i) {
    int cid = i * 256 + tid;
    int kr = cid >> 3, c = cid & 7;
    const float* f = W + (size_t)(k0 + kr) * 1024 + n0 + c * 8;
#pragma unroll
    for (int j = 0; j < 8; ++j) Lt[(c * 8 + j) * 68 + kr] = f2bf(f[j]);
  }
  __syncthreads();
#pragma unroll
  for (int i = 0; i < 2; ++i) {
    int cid = i * 256 + tid;
    int nr = cid >> 3, c = cid & 7;
    u16x8 v;
#pragma unroll
    for (int j = 0; j < 8; ++j) v[j] = Lt[nr * 68 + c * 8 + j];
    *(u16x8*)(O + (size_t)(n0 + nr) * 1024 + k0 + c * 8) = v;
  }
}

// ---------- gemm_bt: C[M][1024] = (A[M][1024] * Bt[1024][1024]^T) * scale ----------
template <int SCATTER, int OUT_F32>
__device__ __forceinline__ void gemm_bt_body(const unsigned short* __restrict__ A,
                                             const unsigned short* __restrict__ Bt,
                                             void* __restrict__ Cv,
                                             int row0, int col0, float scale) {
  __shared__ unsigned short As[128 * 64];
  __shared__ unsigned short Bs[128 * 64];
  const int tid  = threadIdx.x;
  const int lane = tid & 63, w = tid >> 6;
  const int quad = lane >> 4, lm = lane & 15;
  const int wr = (w >> 1) * 64, wc = (w & 1) * 64;
  f32x4 acc[4][4] = {};
  for (int kt = 0; kt < 16; ++kt) {
    const int k0 = kt * 64;
    __syncthreads();
#pragma unroll
    for (int i = 0; i < 4; ++i) {
      int cid = i * 256 + tid;
      int r = cid >> 3, c = cid & 7;
      int cg = c ^ (r & 7);                          // swizzle on SOURCE address
      int base = (i * 256 + (tid & 192)) * 8;        // wave-uniform LDS dst (u16)
      GLOAD_LDS16(A  + (size_t)(row0 + r) * 1024 + k0 + cg * 8, As + base);
      GLOAD_LDS16(Bt + (size_t)(col0 + r) * 1024 + k0 + cg * 8, Bs + base);
    }
    __syncthreads();
#pragma unroll
    for (int kh = 0; kh < 2; ++kh) {
      short8 af[4], bf[4];
#pragma unroll
      for (int t = 0; t < 4; ++t) {
        int ca = (kh * 4 + quad) ^ (lm & 7);
        af[t] = *(const short8*)(As + (wr + t * 16 + lm) * 64 + ca * 8);
        bf[t] = *(const short8*)(Bs + (wc + t * 16 + lm) * 64 + ca * 8);
      }
#pragma unroll
      for (int rt = 0; rt < 4; ++rt)
#pragma unroll
        for (int ct = 0; ct < 4; ++ct)
          acc[rt][ct] = MFMA_BF16(af[rt], bf[ct], acc[rt][ct]);
    }
  }
#pragma unroll
  for (int rt = 0; rt < 4; ++rt)
#pragma unroll
    for (int ct = 0; ct < 4; ++ct)
#pragma unroll
      for (int g = 0; g < 4; ++g) {
        int R  = row0 + wr + rt * 16 + quad * 4 + g;
        int Cc = col0 + wc + ct * 16 + lm;
        int Rs = SCATTER ? row_to_seq(R) : R;
        float vv = acc[rt][ct][g] * scale;
        if (OUT_F32) ((float*)Cv)[(size_t)Rs * 1024 + Cc] = vv;
        else ((unsigned short*)Cv)[(size_t)Rs * 1024 + Cc] = f2bf(vv);
      }
}

// ---------- gemm_qkv3: the 3 QKV GEMMs fused, SHARED A-staging ----------
__global__ __launch_bounds__(256) void gemm_qkv3(const unsigned short* __restrict__ A,
                                                 const unsigned short* __restrict__ Wt,
                                                 unsigned short* __restrict__ QKV) {
  __shared__ unsigned short As[128 * 64];
  __shared__ unsigned short Bs[3][64 * 64];
  const int tid  = threadIdx.x;
  const int lane = tid & 63, w = tid >> 6;
  const int quad = lane >> 4, lm = lane & 15;
  const int wr = (w >> 1) * 64, wc = (w & 1) * 32;   // wave tile 64x32
  const int row0 = blockIdx.y * 128, col0 = blockIdx.x * 64;
  f32x4 acc[3][4][2] = {};
  for (int kt = 0; kt < 16; ++kt) {
    const int k0 = kt * 64;
    __syncthreads();
#pragma unroll
    for (int i = 0; i < 4; ++i) {                    // stage A (4 passes)
      int cid = i * 256 + tid;
      int r = cid >> 3, c = cid & 7;
      int cg = c ^ (r & 7);
      int base = (i * 256 + (tid & 192)) * 8;
      GLOAD_LDS16(A + (size_t)(row0 + r) * 1024 + k0 + cg * 8, As + base);
    }
#pragma unroll
    for (int m = 0; m < 3; ++m)                      // stage 3 B tiles (2 passes each)
#pragma unroll
      for (int i = 0; i < 2; ++i) {
        int cid = i * 256 + tid;
        int r = cid >> 3, c = cid & 7;
        int cg = c ^ (r & 7);
        int base = (i * 256 + (tid & 192)) * 8;
        GLOAD_LDS16(Wt + (size_t)m * 1048576 + (size_t)(col0 + r) * 1024 + k0 + cg * 8,
                    Bs[m] + base);
      }
    __syncthreads();
#pragma unroll
    for (int kh = 0; kh < 2; ++kh) {
      const int ca = (kh * 4 + quad) ^ (lm & 7);
      short8 af[4], bf[3][2];
#pragma unroll
      for (int t = 0; t < 4; ++t)
        af[t] = *(const short8*)(As + (wr + t * 16 + lm) * 64 + ca * 8);
#pragma unroll
      for (int m = 0; m < 3; ++m)
#pragma unroll
        for (int u = 0; u < 2; ++u)
          bf[m][u] = *(const short8*)(Bs[m] + (wc + u * 16 + lm) * 64 + ca * 8);
#pragma unroll
      for (int m = 0; m < 3; ++m)
#pragma unroll
        for (int t = 0; t < 4; ++t)
#pragma unroll
          for (int u = 0; u < 2; ++u)
            acc[m][t][u] = MFMA_BF16(af[t], bf[m][u], acc[m][t][u]);
    }
  }
#pragma unroll
  for (int m = 0; m < 3; ++m) {
    // fold softmax scale (1/8)*log2(e) into Q so attn's exp2 needs no multiply
    const float scale = (m == 0) ? 0.18033688011112042f : 1.0f;
    unsigned short* Cm = QKV + (size_t)m * 8388608;
#pragma unroll
    for (int t = 0; t < 4; ++t)
#pragma unroll
      for (int u = 0; u < 2; ++u)
#pragma unroll
        for (int g = 0; g < 4; ++g) {
          int R  = row0 + wr + t * 16 + quad * 4 + g;
          int Cc = col0 + wc + u * 16 + lm;
          Cm[(size_t)R * 1024 + Cc] = f2bf(acc[m][t][u][g] * scale);
        }
  }
}

__global__ __launch_bounds__(256) void gemm_out(const unsigned short* __restrict__ A,
                                                const unsigned short* __restrict__ Wt,
                                                float* __restrict__ Cout) {
  gemm_bt_body<1, 1>(A, Wt, Cout, blockIdx.y * 128, blockIdx.x * 128, 1.0f);
}

// ---------- kernel: V [8192][16*64] (tile rows) -> Vt [16][64][8192] ----------
__global__ __launch_bounds__(256) void transpose_v(const unsigned short* __restrict__ V,
                                                   unsigned short* __restrict__ Vt) {
  __shared__ unsigned short Lt[64 * 136];            // [d][r] tile, pad 136
  int kt = blockIdx.x, h = blockIdx.y, tid = threadIdx.x;
#pragma unroll
  for (int i = 0; i < 4; ++i) {
    int cid = i * 256 + tid;                         // 1024 chunks
    int r = cid >> 3, c = cid & 7;
    u16x8 v = *(const u16x8*)(V + (size_t)(kt * 128 + r) * 1024 + h * 64 + c * 8);
#pragma unroll
    for (int j = 0; j < 8; ++j) Lt[(c * 8 + j) * 136 + r] = v[j];
  }
  __syncthreads();
#pragma unroll
  for (int i = 0; i < 4; ++i) {
    int cid = i * 256 + tid;
    int d = cid >> 4, c = cid & 15;
    u16x8 v = *(const u16x8*)(Lt + d * 136 + c * 8);
    *(u16x8*)(Vt + (size_t)(h * 64 + d) * 8192 + kt * 128 + c * 8) = v;
  }
}

// ---------- attention: one block per (head, q-tile), 256 threads (4 waves) ----------
// Round-9: 32x32x16 MFMA everywhere — halves LDS bytes per FLOP. Diagnosis
// (r8): attn is LDS-BW-bound (~352 KB/block/iter at ~85 B/cyc ≈ measured dur).
// New: 4 waves x 32 q-rows; per block per iter LDS = K 4x16 + V 4x16 + Pb 16
// + staging 32 = 224 KB (x0.64). Double-buffered K/V, ONE barrier/iter (r7).
// Layouts (guide-verified 32x32x16_bf16): A row=lane&31,k=(lane>>5)*8+j;
// B col=lane&31,k=(lane>>5)*8+j; C col=lane&31,row=(reg&3)+8*(reg>>2)+4*(lane>>5).
// Pb per wave [32 q][64 kv] (4 KB), two kv-halves per iter; chunk ^= q&7.
// LDS: Ks 32 + Vs 32 + Pb 16 = 80 KB -> 2 blocks/CU (8 waves/CU). VGPR budget
// free up to 256 at this occupancy (LDS-capped), so no (512,4)-style 64-cap.
__global__ __launch_bounds__(256) void attn(const unsigned short* __restrict__ Q,
                                            const unsigned short* __restrict__ K,
                                            const unsigned short* __restrict__ Vt,
                                            unsigned short* __restrict__ O) {
  __shared__ unsigned short Ks[2][128 * 64];         // 32 KB [kv][d], swizzled
  __shared__ unsigned short Vs[2][64 * 128];         // 32 KB [d][kv], swizzled
  __shared__ unsigned short Pb[4 * 32 * 64];         // 16 KB: per-wave [32 q][64 kv]

  const int tid  = threadIdx.x;
  const int lane = tid & 63, w = tid >> 6;           // w in 0..3
  const int q31  = lane & 31, l5 = lane >> 5;        // MFMA 32x32 lane split
  unsigned short* Pbw = Pb + w * 2048;               // wave-private [32 q][64 kv]

  const int h = blockIdx.x >> 6, qt = blockIdx.x & 63;
  const int ntt = qt >> 4, nth = (qt >> 2) & 3, ntw = qt & 3;
  const int kt0 = min(max(ntt, 1), 2) - 1;           // t-window start tile
  const int kh0 = min(max(nth, 1), 3) - 1;
  const int kw0 = min(max(ntw, 1), 3) - 1;

  // per-lane invariant staging offsets (u32 element offsets), 4 passes each
  unsigned koff[4], voff[4], ldsD[4];
#pragma unroll
  for (int i = 0; i < 4; ++i) {
    int cid = i * 256 + tid;
    int rK = cid >> 3, cK = cid & 7, cgK = cK ^ (rK & 7);
    koff[i] = rK * 1024 + h * 64 + cgK * 8;
    int dV = cid >> 4, cV = cid & 15, cgV = cV ^ (dV & 7);
    voff[i] = (h * 64 + dV) * 8192 + cgV * 8;
    ldsD[i] = (i * 256 + (tid & 192)) * 8;           // wave-uniform LDS dst (u16)
  }

  // Q B-frags (pre-scaled by CSC): col q = w*32+q31, k = d = ks*16 + l5*8 + j
  short8 bq[4];
#pragma unroll
  for (int ks = 0; ks < 4; ++ks)
    bq[ks] = *(const short8*)(Q + (size_t)(qt * 128 + w * 32 + q31) * 1024
                                + h * 64 + ks * 16 + l5 * 8);

  short8 ones8;
#pragma unroll
  for (int j = 0; j < 8; ++j) ones8[j] = (short)0x3F80;   // bf16 1.0

  f32x16 oA = {}, oB = {};                           // d-blocks 0 (d 0-31), 1 (d 32-63)
  f32x16 l_acc = {};                                 // row sums of P (rows = q, like oA)

  // ---- prologue: stage K[0], V[0] into buf 0, drain, barrier ----
  {
    const int kvt0 = kt0 * 16 + kh0 * 4 + kw0;
    const unsigned k0 = (unsigned)kvt0 << 17;
    const unsigned v0 = (unsigned)kvt0 << 7;
#pragma unroll
    for (int i = 0; i < 4; ++i) GLOAD_LDS16(K  + koff[i] + k0, Ks[0] + ldsD[i]);
#pragma unroll
    for (int i = 0; i < 4; ++i) GLOAD_LDS16(Vt + voff[i] + v0, Vs[0] + ldsD[i]);
  }
  __syncthreads();                                   // K[0],V[0] landed

  for (int it = 0; it < 12; ++it) {
    const int p = it & 1;
    const unsigned short* Ksp = Ks[p];
    const unsigned short* Vsp = Vs[p];

    // issue K[it+1],V[it+1] into buf[1-p]; in flight across this whole iter.
    if (it < 11) {
      const int jt = it + 1;
      const int t2 = jt >> 2, h2 = (jt >> 1) & 1, w2 = jt & 1;
      const int kvn = (kt0 + t2) * 16 + (kh0 + h2) * 4 + (kw0 + w2);
      const unsigned kn = (unsigned)kvn << 17;
      const unsigned vn = (unsigned)kvn << 7;
#pragma unroll
      for (int i = 0; i < 4; ++i) GLOAD_LDS16(K  + koff[i] + kn, Ks[1 - p] + ldsD[i]);
#pragma unroll
      for (int i = 0; i < 4; ++i) GLOAD_LDS16(Vt + voff[i] + vn, Vs[1 - p] + ldsD[i]);
    }

#pragma unroll
    for (int half = 0; half < 2; ++half) {
      // ---- QK^T: S^T[64 kv (this half)][32 q] in two 32x32 kv-blocks ----
#pragma unroll
      for (int kvb = 0; kvb < 2; ++kvb) {
        f32x16 sa = {};
        const int kvrow = half * 64 + kvb * 32 + q31;   // kvrow&7 == q31&7
        short8 ak[4];
#pragma unroll
        for (int ks = 0; ks < 4; ++ks)
          ak[ks] = *(const short8*)(Ksp + kvrow * 64 + (((ks * 2 + l5) ^ (q31 & 7)) * 8));
        __builtin_amdgcn_s_setprio(1);
#pragma unroll
        for (int ks = 0; ks < 4; ++ks) sa = MFMA32(ak[ks], bq[ks], sa);
        __builtin_amdgcn_s_setprio(0);
        // P = exp2(S^T); regs 4rg+{0..3} = kv (8rg + 4*l5 + {0..3}) of this kv-block
#pragma unroll
        for (int rg = 0; rg < 4; ++rg) {
          u32x2 pk2;
          pk2[0] = pack2bf(exp2f(sa[4 * rg + 0]), exp2f(sa[4 * rg + 1]));
          pk2[1] = pack2bf(exp2f(sa[4 * rg + 2]), exp2f(sa[4 * rg + 3]));
          // chunk = kvb*4+rg (8 kv each), 8B sub = l5, chunk ^= q&7
          *(u32x2*)(Pbw + q31 * 64 + (((kvb * 4 + rg) ^ (q31 & 7)) * 8) + l5 * 4) = pk2;
        }
      }
      // ---- PV for this half: O[32 q][64 d] += P x V ; l += P x 1 ----
      // Pbw wave-private; same-wave LDS ops are ordered (write->read safe).
#pragma unroll
      for (int ks = 0; ks < 4; ++ks) {
        short8 ap  = *(const short8*)(Pbw + q31 * 64 + (((ks * 2 + l5) ^ (q31 & 7)) * 8));
        short8 bv0 = *(const short8*)(Vsp + (q31) * 128
                                      + (((half * 8 + ks * 2 + l5) ^ (q31 & 7)) * 8));
        short8 bv1 = *(const short8*)(Vsp + (32 + q31) * 128
                                      + (((half * 8 + ks * 2 + l5) ^ (q31 & 7)) * 8));
        __builtin_amdgcn_s_setprio(1);
        l_acc = MFMA32(ap, ones8, l_acc);
        oA = MFMA32(ap, bv0, oA);
        oB = MFMA32(ap, bv1, oB);
        __builtin_amdgcn_s_setprio(0);
      }
    }

    // ONE barrier: drains vmcnt (buf[1-p] staged) and licenses overwriting buf[p].
    __syncthreads();
  }

  // normalize by l and store; C layout: col=lane&31, row=(r&3)+8*(r>>2)+4*l5
#pragma unroll
  for (int r = 0; r < 16; ++r) {
    float inv = 1.0f / l_acc[r];
    int row = (r & 3) + 8 * (r >> 2) + 4 * l5;
    size_t R = (size_t)(qt * 128 + w * 32 + row) * 1024 + h * 64 + q31;
    O[R]      = f2bf(oA[r] * inv);
    O[R + 32] = f2bf(oB[r] * inv);
  }
}

// ---------- host ----------
extern "C" void kernel_launch(void* const* d_in, const int* in_sizes, int n_in,
                              void* d_out, int out_size, void* d_ws, size_t ws_size,
                              hipStream_t stream) {
  const float* hs = (const float*)d_in[0];
  const float* wq = (const float*)d_in[1];
  const float* wk = (const float*)d_in[2];
  const float* wv = (const float*)d_in[3];
  const float* wo = (const float*)d_in[4];
  float* out = (float*)d_out;                        // reference output dtype = float32

  const size_t NEL = 8388608;                        // 8192*1024
  unsigned short* ws  = (unsigned short*)d_ws;
  unsigned short* HSt = ws;                          // [8192][1024] tile-ordered
  unsigned short* Qb  = ws + 1 * NEL;
  unsigned short* Kb  = ws + 2 * NEL;
  unsigned short* Vb  = ws + 3 * NEL;
  unsigned short* Vtb = ws + 4 * NEL;                // [16][64][8192]
  unsigned short* Ot  = ws + 5 * NEL;
  unsigned short* Wt  = ws + 6 * NEL;                // 4 x [1024][1024] transposed
  if (ws_size < (6 * NEL + 4 * 1048576) * sizeof(unsigned short)) return;

  permute_hs<<<4096, 256, 0, stream>>>(hs, HSt);
  transpose_w<<<dim3(256, 4), 256, 0, stream>>>(wq, wk, wv, wo, Wt);
  gemm_qkv3<<<dim3(16, 64), 256, 0, stream>>>(HSt, Wt, Qb);
  transpose_v<<<dim3(64, 16), 256, 0, stream>>>(Vb, Vtb);
  attn<<<1024, 256, 0, stream>>>(Qb, Kb, Vtb, Ot);
  gemm_out<<<dim3(8, 64, 1), 256, 0, stream>>>(Ot, Wt + 3 * 1048576, out);
  (void)in_sizes; (void)n_in; (void)out_size;
}

// Round 10
// 256.383 us; speedup vs baseline: 1.1014x; 1.1014x over previous
//
#include <hip/hip_runtime.h>
#include <hip/hip_bf16.h>
#include <math.h>

// ---------- types ----------
typedef __attribute__((ext_vector_type(8))) short          short8;   // 8 bf16 (MFMA frag)
typedef __attribute__((ext_vector_type(8))) unsigned short u16x8;    // 16B chunk
typedef __attribute__((ext_vector_type(2))) unsigned int   u32x2;    // 8B chunk
typedef __attribute__((ext_vector_type(4))) float          f32x4;    // MFMA acc

#define MFMA_BF16(a, b, c) __builtin_amdgcn_mfma_f32_16x16x32_bf16((a), (b), (c), 0, 0, 0)

// async global->LDS, 16B per lane; LDS dst = wave-uniform base + lane*16
#define GLOAD_LDS16(gp, lp)                                        \
  __builtin_amdgcn_global_load_lds(                                \
      (const __attribute__((address_space(1))) void*)(gp),         \
      (__attribute__((address_space(3))) void*)(lp), 16, 0, 0)

// B=1, HID=1024, NH=16, D=64, S=8192, TILE=128, NTILE=64, 12 kv tiles/q tile
// Inputs fp32, output fp32 (verified rounds 1/5).

__device__ __forceinline__ unsigned short f2bf(float f) {
  union { float f; unsigned int u; } v; v.f = f;
  unsigned int r = v.u + 0x7fffu + ((v.u >> 16) & 1u);   // RNE
  return (unsigned short)(r >> 16);
}
// pack two positive floats to a bf16 pair in ONE VALU op (a -> low 16, b -> high).
__device__ __forceinline__ unsigned int pack2bf(float a, float b) {
  unsigned int r;
  asm("v_cvt_pk_bf16_f32 %0, %1, %2" : "=v"(r) : "v"(a), "v"(b));
  return r;
}
// raw HW exp2: ONE quarter-rate VALU op. Without fast-math, exp2f lowers to
// __ocml_exp2_f32 (~10 VALU ops of range fixup) — that was ~half of attn's
// VALUBusy (r9 post-mortem). Our scores are range-safe; v_exp_f32 saturates
// to 0/inf identically for the bf16-rounded result.
__device__ __forceinline__ float exp2_hw(float x) {
  float r;
  asm("v_exp_f32 %0, %1" : "=v"(r) : "v"(x));
  return r;
}

// tile-order row r -> natural sequence index s
__device__ __forceinline__ int row_to_seq(int r) {
  int tile = r >> 7, pos = r & 127;
  int ntt = tile >> 4, nth = (tile >> 2) & 3, ntw = tile & 3;
  int tt  = pos >> 6,  th  = (pos >> 3) & 7,  tw  = pos & 7;
  return ((ntt * 2 + tt) << 10) | ((nth * 8 + th) << 5) | (ntw * 8 + tw);
}

// ---------- kernel 1: permute hidden_states rows into tile order (+cast fp32->bf16) ----------
__global__ __launch_bounds__(256) void permute_hs(const float* __restrict__ in,
                                                  unsigned short* __restrict__ out) {
  int cid = blockIdx.x * 256 + threadIdx.x;          // 1,048,576 chunks of 8 elems
  int r = cid >> 7, c = (cid & 127) * 8;
  int s = row_to_seq(r);
  const float* f = in + (size_t)s * 1024 + c;
  u16x8 v;
#pragma unroll
  for (int j = 0; j < 8; ++j) v[j] = f2bf(f[j]);
  *(u16x8*)(out + (size_t)r * 1024 + c) = v;
}

// ---------- kernel 2: transpose the 4 weight matrices [K][N] -> [N][K] (+cast) ----------
__global__ __launch_bounds__(256) void transpose_w(const float* __restrict__ w0,
                                                   const float* __restrict__ w1,
                                                   const float* __restrict__ w2,
                                                   const float* __restrict__ w3,
                                                   unsigned short* __restrict__ out) {
  __shared__ unsigned short Lt[64 * 68];             // [n][k] tile, pad 68
  int m = blockIdx.y;
  const float* W = (m == 0) ? w0 : (m == 1) ? w1 : (m == 2) ? w2 : w3;
  unsigned short* O = out + (size_t)m * 1048576;
  int k0 = (blockIdx.x >> 4) * 64, n0 = (blockIdx.x & 15) * 64;
  int tid = threadIdx.x;
#pragma unroll
  for (int i = 0; i < 2; ++i) {
    int cid = i * 256 + tid;
    int kr = cid >> 3, c = cid & 7;
    const float* f = W + (size_t)(k0 + kr) * 1024 + n0 + c * 8;
#pragma unroll
    for (int j = 0; j < 8; ++j) Lt[(c * 8 + j) * 68 + kr] = f2bf(f[j]);
  }
  __syncthreads();
#pragma unroll
  for (int i = 0; i < 2; ++i) {
    int cid = i * 256 + tid;
    int nr = cid >> 3, c = cid & 7;
    u16x8 v;
#pragma unroll
    for (int j = 0; j < 8; ++j) v[j] = Lt[nr * 68 + c * 8 + j];
    *(u16x8*)(O + (size_t)(n0 + nr) * 1024 + k0 + c * 8) = v;
  }
}

// ---------- gemm_bt: C[M][1024] = (A[M][1024] * Bt[1024][1024]^T) * scale ----------
template <int SCATTER, int OUT_F32>
__device__ __forceinline__ void gemm_bt_body(const unsigned short* __restrict__ A,
                                             const unsigned short* __restrict__ Bt,
                                             void* __restrict__ Cv,
                                             int row0, int col0, float scale) {
  __shared__ unsigned short As[128 * 64];
  __shared__ unsigned short Bs[128 * 64];
  const int tid  = threadIdx.x;
  const int lane = tid & 63, w = tid >> 6;
  const int quad = lane >> 4, lm = lane & 15;
  const int wr = (w >> 1) * 64, wc = (w & 1) * 64;
  f32x4 acc[4][4] = {};
  for (int kt = 0; kt < 16; ++kt) {
    const int k0 = kt * 64;
    __syncthreads();
#pragma unroll
    for (int i = 0; i < 4; ++i) {
      int cid = i * 256 + tid;
      int r = cid >> 3, c = cid & 7;
      int cg = c ^ (r & 7);                          // swizzle on SOURCE address
      int base = (i * 256 + (tid & 192)) * 8;        // wave-uniform LDS dst (u16)
      GLOAD_LDS16(A  + (size_t)(row0 + r) * 1024 + k0 + cg * 8, As + base);
      GLOAD_LDS16(Bt + (size_t)(col0 + r) * 1024 + k0 + cg * 8, Bs + base);
    }
    __syncthreads();
#pragma unroll
    for (int kh = 0; kh < 2; ++kh) {
      short8 af[4], bf[4];
#pragma unroll
      for (int t = 0; t < 4; ++t) {
        int ca = (kh * 4 + quad) ^ (lm & 7);
        af[t] = *(const short8*)(As + (wr + t * 16 + lm) * 64 + ca * 8);
        bf[t] = *(const short8*)(Bs + (wc + t * 16 + lm) * 64 + ca * 8);
      }
#pragma unroll
      for (int rt = 0; rt < 4; ++rt)
#pragma unroll
        for (int ct = 0; ct < 4; ++ct)
          acc[rt][ct] = MFMA_BF16(af[rt], bf[ct], acc[rt][ct]);
    }
  }
#pragma unroll
  for (int rt = 0; rt < 4; ++rt)
#pragma unroll
    for (int ct = 0; ct < 4; ++ct)
#pragma unroll
      for (int g = 0; g < 4; ++g) {
        int R  = row0 + wr + rt * 16 + quad * 4 + g;
        int Cc = col0 + wc + ct * 16 + lm;
        int Rs = SCATTER ? row_to_seq(R) : R;
        float vv = acc[rt][ct][g] * scale;
        if (OUT_F32) ((float*)Cv)[(size_t)Rs * 1024 + Cc] = vv;
        else ((unsigned short*)Cv)[(size_t)Rs * 1024 + Cc] = f2bf(vv);
      }
}

// ---------- gemm_qkv3: the 3 QKV GEMMs fused, SHARED A-staging (r8, kept) ----------
__global__ __launch_bounds__(256) void gemm_qkv3(const unsigned short* __restrict__ A,
                                                 const unsigned short* __restrict__ Wt,
                                                 unsigned short* __restrict__ QKV) {
  __shared__ unsigned short As[128 * 64];
  __shared__ unsigned short Bs[3][64 * 64];
  const int tid  = threadIdx.x;
  const int lane = tid & 63, w = tid >> 6;
  const int quad = lane >> 4, lm = lane & 15;
  const int wr = (w >> 1) * 64, wc = (w & 1) * 32;   // wave tile 64x32
  const int row0 = blockIdx.y * 128, col0 = blockIdx.x * 64;
  f32x4 acc[3][4][2] = {};
  for (int kt = 0; kt < 16; ++kt) {
    const int k0 = kt * 64;
    __syncthreads();
#pragma unroll
    for (int i = 0; i < 4; ++i) {                    // stage A (4 passes)
      int cid = i * 256 + tid;
      int r = cid >> 3, c = cid & 7;
      int cg = c ^ (r & 7);
      int base = (i * 256 + (tid & 192)) * 8;
      GLOAD_LDS16(A + (size_t)(row0 + r) * 1024 + k0 + cg * 8, As + base);
    }
#pragma unroll
    for (int m = 0; m < 3; ++m)                      // stage 3 B tiles (2 passes each)
#pragma unroll
      for (int i = 0; i < 2; ++i) {
        int cid = i * 256 + tid;
        int r = cid >> 3, c = cid & 7;
        int cg = c ^ (r & 7);
        int base = (i * 256 + (tid & 192)) * 8;
        GLOAD_LDS16(Wt + (size_t)m * 1048576 + (size_t)(col0 + r) * 1024 + k0 + cg * 8,
                    Bs[m] + base);
      }
    __syncthreads();
#pragma unroll
    for (int kh = 0; kh < 2; ++kh) {
      const int ca = (kh * 4 + quad) ^ (lm & 7);
      short8 af[4], bf[3][2];
#pragma unroll
      for (int t = 0; t < 4; ++t)
        af[t] = *(const short8*)(As + (wr + t * 16 + lm) * 64 + ca * 8);
#pragma unroll
      for (int m = 0; m < 3; ++m)
#pragma unroll
        for (int u = 0; u < 2; ++u)
          bf[m][u] = *(const short8*)(Bs[m] + (wc + u * 16 + lm) * 64 + ca * 8);
#pragma unroll
      for (int m = 0; m < 3; ++m)
#pragma unroll
        for (int t = 0; t < 4; ++t)
#pragma unroll
          for (int u = 0; u < 2; ++u)
            acc[m][t][u] = MFMA_BF16(af[t], bf[m][u], acc[m][t][u]);
    }
  }
#pragma unroll
  for (int m = 0; m < 3; ++m) {
    // fold softmax scale (1/8)*log2(e) into Q so attn's exp2 needs no multiply
    const float scale = (m == 0) ? 0.18033688011112042f : 1.0f;
    unsigned short* Cm = QKV + (size_t)m * 8388608;
#pragma unroll
    for (int t = 0; t < 4; ++t)
#pragma unroll
      for (int u = 0; u < 2; ++u)
#pragma unroll
        for (int g = 0; g < 4; ++g) {
          int R  = row0 + wr + t * 16 + quad * 4 + g;
          int Cc = col0 + wc + u * 16 + lm;
          Cm[(size_t)R * 1024 + Cc] = f2bf(acc[m][t][u][g] * scale);
        }
  }
}

__global__ __launch_bounds__(256) void gemm_out(const unsigned short* __restrict__ A,
                                                const unsigned short* __restrict__ Wt,
                                                float* __restrict__ Cout) {
  gemm_bt_body<1, 1>(A, Wt, Cout, blockIdx.y * 128, blockIdx.x * 128, 1.0f);
}

// ---------- kernel: V [8192][16*64] (tile rows) -> Vt [16][64][8192] ----------
__global__ __launch_bounds__(256) void transpose_v(const unsigned short* __restrict__ V,
                                                   unsigned short* __restrict__ Vt) {
  __shared__ unsigned short Lt[64 * 136];            // [d][r] tile, pad 136
  int kt = blockIdx.x, h = blockIdx.y, tid = threadIdx.x;
#pragma unroll
  for (int i = 0; i < 4; ++i) {
    int cid = i * 256 + tid;                         // 1024 chunks
    int r = cid >> 3, c = cid & 7;
    u16x8 v = *(const u16x8*)(V + (size_t)(kt * 128 + r) * 1024 + h * 64 + c * 8);
#pragma unroll
    for (int j = 0; j < 8; ++j) Lt[(c * 8 + j) * 136 + r] = v[j];
  }
  __syncthreads();
#pragma unroll
  for (int i = 0; i < 4; ++i) {
    int cid = i * 256 + tid;
    int d = cid >> 4, c = cid & 15;
    u16x8 v = *(const u16x8*)(Lt + d * 136 + c * 8);
    *(u16x8*)(Vt + (size_t)(h * 64 + d) * 8192 + kt * 128 + c * 8) = v;
  }
}

// ---------- attention: one block per (head, q-tile), 512 threads (8 waves) ----------
// Round-10 = round-6 structure (measured best: 94.3 us; 16x16 MFMA, 48 KB LDS,
// 3 blocks/CU, 2 barriers/iter, V[it]-at-top / K[it+1]-after-mid pipelining,
// precomputed staging offsets, cvt_pk P-pack) + raw v_exp_f32 (exp2_hw).
// r9 lesson: 32x32 MFMA halves LDS bytes but collapses occupancy (2 waves/SIMD)
// and 4-way-conflicts the K reads — net regression. r7 lesson: dbuf+1-barrier
// trades residency for sync, net zero. (512,4): allocator settles <=64 VGPR;
// bigger live sets spill 10x (r3/r5).
__global__ __launch_bounds__(512, 4) void attn(const unsigned short* __restrict__ Q,
                                               const unsigned short* __restrict__ K,
                                               const unsigned short* __restrict__ Vt,
                                               unsigned short* __restrict__ O) {
  __shared__ unsigned short Ks[128 * 64];            // 16 KB [kv][d], swizzled
  __shared__ unsigned short Vs[64 * 128];            // 16 KB [d][kv], swizzled
  __shared__ unsigned short Pb[8 * 16 * 64];         // 16 KB: per-wave 2 KB P slice

  const int tid  = threadIdx.x;
  const int lane = tid & 63, w = tid >> 6;           // w in 0..7
  const int quad = lane >> 4, lm = lane & 15;
  unsigned short* Pbw = Pb + w * 1024;               // wave-private [q 16][kv 64]

  const int h = blockIdx.x >> 6, qt = blockIdx.x & 63;
  const int ntt = qt >> 4, nth = (qt >> 2) & 3, ntw = qt & 3;
  const int kt0 = min(max(ntt, 1), 2) - 1;           // t-window start tile
  const int kh0 = min(max(nth, 1), 3) - 1;
  const int kw0 = min(max(ntw, 1), 3) - 1;

  // per-lane invariant staging offsets (u32 element offsets)
  const int cid1 = 512 + tid;
  const int rK0 = tid  >> 3, cgK0 = (tid  & 7) ^ (rK0 & 7);
  const int rK1 = cid1 >> 3, cgK1 = (cid1 & 7) ^ (rK1 & 7);
  const unsigned koff0 = rK0 * 1024 + h * 64 + cgK0 * 8;
  const unsigned koff1 = rK1 * 1024 + h * 64 + cgK1 * 8;
  const int dV0 = tid  >> 4, cgV0 = (tid  & 15) ^ (dV0 & 7);
  const int dV1 = cid1 >> 4, cgV1 = (cid1 & 15) ^ (dV1 & 7);
  const unsigned voff0 = (h * 64 + dV0) * 8192 + cgV0 * 8;
  const unsigned voff1 = (h * 64 + dV1) * 8192 + cgV1 * 8;
  const unsigned ldsD0 = (tid & 448) * 8;            // wave-uniform LDS dst (u16)
  const unsigned ldsD1 = (512 + (tid & 448)) * 8;

  // Q B-frags (Q pre-scaled by CSC): n=q = w*16+lm, k=d = kh*32+quad*8+j
  short8 bq[2];
#pragma unroll
  for (int kh = 0; kh < 2; ++kh)
    bq[kh] = *(const short8*)(Q + (size_t)(qt * 128 + w * 16 + lm) * 1024
                                + h * 64 + kh * 32 + quad * 8);

  short8 ones8;
#pragma unroll
  for (int j = 0; j < 8; ++j) ones8[j] = (short)0x3F80;   // bf16 1.0

  f32x4 o_acc[4] = {};                               // [d-tile]
  f32x4 l_acc = {};                                  // row sums of P

  // ---- prologue: stage K tile 0, drain, barrier ----
  {
    const unsigned k0 = (unsigned)(kt0 * 16 + kh0 * 4 + kw0) << 17;
    GLOAD_LDS16(K + koff0 + k0, Ks + ldsD0);
    GLOAD_LDS16(K + koff1 + k0, Ks + ldsD1);
  }
  __syncthreads();                                   // K[0] landed

  for (int it = 0; it < 12; ++it) {
    const int tt2 = it >> 2, hh2 = (it >> 1) & 1, ww2 = it & 1;
    const int kvt = (kt0 + tt2) * 16 + (kh0 + hh2) * 4 + (kw0 + ww2);

    // issue V[it] (latency hidden under QK^T + exp2)
    {
      const unsigned v0 = (unsigned)kvt << 7;
      GLOAD_LDS16(Vt + voff0 + v0, Vs + ldsD0);
      GLOAD_LDS16(Vt + voff1 + v0, Vs + ldsD1);
    }

    // S^T[kv 128][q 16(wave)] = K * Q^T
    f32x4 sa[8] = {};                                // [kv-tile rt]
#pragma unroll
    for (int kh = 0; kh < 2; ++kh) {
      short8 ak[8];
#pragma unroll
      for (int rt = 0; rt < 8; ++rt)
        ak[rt] = *(const short8*)(Ks + (rt * 16 + lm) * 64 + (((kh * 4 + quad) ^ (lm & 7)) * 8));
      __builtin_amdgcn_s_setprio(1);
#pragma unroll
      for (int rt = 0; rt < 8; ++rt)
        sa[rt] = MFMA_BF16(ak[rt], bq[kh], sa[rt]);
      __builtin_amdgcn_s_setprio(0);
    }

    // P = exp2(S^T) packed to bf16 pairs, kept in registers across the barrier
    u32x2 pk[8];
#pragma unroll
    for (int rt = 0; rt < 8; ++rt) {
      pk[rt][0] = pack2bf(exp2_hw(sa[rt][0]), exp2_hw(sa[rt][1]));
      pk[rt][1] = pack2bf(exp2_hw(sa[rt][2]), exp2_hw(sa[rt][3]));
    }

    __syncthreads();   // drains vmcnt -> V[it] landed; all waves done reading Ks

    // prefetch K[it+1] into Ks (latency hidden under PV)
    if (it < 11) {
      const int jt = it + 1;
      const int t2 = jt >> 2, h2 = (jt >> 1) & 1, w2 = jt & 1;
      const unsigned kn = (unsigned)((kt0 + t2) * 16 + (kh0 + h2) * 4 + (kw0 + w2)) << 17;
      GLOAD_LDS16(K + koff0 + kn, Ks + ldsD0);
      GLOAD_LDS16(K + koff1 + kn, Ks + ldsD1);
    }

    // O += P * V ; l += P * 1  — two kv-halves through the 2 KB Pb slice.
    // Same-wave LDS ops are processed in order, so half-1 writes cannot pass
    // half-0 reads; Pbw is wave-private so no barrier is needed.
#pragma unroll
    for (int half = 0; half < 2; ++half) {
#pragma unroll
      for (int rt4 = 0; rt4 < 4; ++rt4) {
        // kv offset rt4*16+quad*4 -> chunk 2rt4+(quad>>1), 8B half quad&1, chunk ^= lm&7
        *(u32x2*)(Pbw + lm * 64 + (((rt4 * 2 + (quad >> 1)) ^ (lm & 7)) * 8) + (quad & 1) * 4)
            = pk[half * 4 + rt4];
      }
#pragma unroll
      for (int ks2 = 0; ks2 < 2; ++ks2) {
        short8 ap = *(const short8*)(Pbw + lm * 64 + (((ks2 * 4 + quad) ^ (lm & 7)) * 8));
        const int ks = half * 2 + ks2;
        short8 bv[4];
#pragma unroll
        for (int nt = 0; nt < 4; ++nt)
          bv[nt] = *(const short8*)(Vs + (nt * 16 + lm) * 128 + (((ks * 4 + quad) ^ (lm & 7)) * 8));
        __builtin_amdgcn_s_setprio(1);
        l_acc = MFMA_BF16(ap, ones8, l_acc);
#pragma unroll
        for (int nt = 0; nt < 4; ++nt)
          o_acc[nt] = MFMA_BF16(ap, bv[nt], o_acc[nt]);
        __builtin_amdgcn_s_setprio(0);
      }
    }

    __syncthreads();   // drains vmcnt -> K[it+1] landed; all waves done reading Vs
  }

  // normalize by l and store (rows q = quad*4+g -> per-lane l)
#pragma unroll
  for (int g = 0; g < 4; ++g) {
    float inv = 1.0f / l_acc[g];
#pragma unroll
    for (int nt = 0; nt < 4; ++nt) {
      int R = qt * 128 + w * 16 + quad * 4 + g;
      O[(size_t)R * 1024 + h * 64 + nt * 16 + lm] = f2bf(o_acc[nt][g] * inv);
    }
  }
}

// ---------- host ----------
extern "C" void kernel_launch(void* const* d_in, const int* in_sizes, int n_in,
                              void* d_out, int out_size, void* d_ws, size_t ws_size,
                              hipStream_t stream) {
  const float* hs = (const float*)d_in[0];
  const float* wq = (const float*)d_in[1];
  const float* wk = (const float*)d_in[2];
  const float* wv = (const float*)d_in[3];
  const float* wo = (const float*)d_in[4];
  float* out = (float*)d_out;                        // reference output dtype = float32

  const size_t NEL = 8388608;                        // 8192*1024
  unsigned short* ws  = (unsigned short*)d_ws;
  unsigned short* HSt = ws;                          // [8192][1024] tile-ordered
  unsigned short* Qb  = ws + 1 * NEL;
  unsigned short* Kb  = ws + 2 * NEL;
  unsigned short* Vb  = ws + 3 * NEL;
  unsigned short* Vtb = ws + 4 * NEL;                // [16][64][8192]
  unsigned short* Ot  = ws + 5 * NEL;
  unsigned short* Wt  = ws + 6 * NEL;                // 4 x [1024][1024] transposed
  if (ws_size < (6 * NEL + 4 * 1048576) * sizeof(unsigned short)) return;

  permute_hs<<<4096, 256, 0, stream>>>(hs, HSt);
  transpose_w<<<dim3(256, 4), 256, 0, stream>>>(wq, wk, wv, wo, Wt);
  gemm_qkv3<<<dim3(16, 64), 256, 0, stream>>>(HSt, Wt, Qb);
  transpose_v<<<dim3(64, 16), 256, 0, stream>>>(Vb, Vtb);
  attn<<<1024, 512, 0, stream>>>(Qb, Kb, Vtb, Ot);
  gemm_out<<<dim3(8, 64, 1), 256, 0, stream>>>(Ot, Wt + 3 * 1048576, out);
  (void)in_sizes; (void)n_in; (void)out_size;
}

// Round 13
// 252.602 us; speedup vs baseline: 1.1179x; 1.0150x over previous
//
#include <hip/hip_runtime.h>
#include <hip/hip_bf16.h>
#include <math.h>

// ---------- types ----------
typedef __attribute__((ext_vector_type(8))) short          short8;   // 8 bf16 (MFMA frag)
typedef __attribute__((ext_vector_type(8))) unsigned short u16x8;    // 16B chunk
typedef __attribute__((ext_vector_type(2))) unsigned int   u32x2;    // 8B chunk
typedef __attribute__((ext_vector_type(4))) float          f32x4;    // MFMA acc

#define MFMA_BF16(a, b, c) __builtin_amdgcn_mfma_f32_16x16x32_bf16((a), (b), (c), 0, 0, 0)

// async global->LDS, 16B per lane; LDS dst = wave-uniform base + lane*16
#define GLOAD_LDS16(gp, lp)                                        \
  __builtin_amdgcn_global_load_lds(                                \
      (const __attribute__((address_space(1))) void*)(gp),         \
      (__attribute__((address_space(3))) void*)(lp), 16, 0, 0)

// B=1, HID=1024, NH=16, D=64, S=8192, TILE=128, NTILE=64, 12 kv tiles/q tile
// Inputs fp32, output fp32 (verified rounds 1/5).

__device__ __forceinline__ unsigned short f2bf(float f) {
  union { float f; unsigned int u; } v; v.f = f;
  unsigned int r = v.u + 0x7fffu + ((v.u >> 16) & 1u);   // RNE
  return (unsigned short)(r >> 16);
}
// pack two positive floats to a bf16 pair in ONE VALU op (a -> low 16, b -> high).
__device__ __forceinline__ unsigned int pack2bf(float a, float b) {
  unsigned int r;
  asm("v_cvt_pk_bf16_f32 %0, %1, %2" : "=v"(r) : "v"(a), "v"(b));
  return r;
}
// raw HW exp2: ONE quarter-rate VALU op (r10: VALUBusy 55->30, attn -14 us).
// NOTE (r11/r12 lesson): the paired-tile 32x32 composition failed with BOTH
// asm and builtin exp2 -> the failure there was a race in that composition,
// not this instruction. In the r10 16x16 structure this asm is verified.
__device__ __forceinline__ float exp2_hw(float x) {
  float r;
  asm("v_exp_f32 %0, %1" : "=v"(r) : "v"(x));
  return r;
}

// tile-order row r -> natural sequence index s
__device__ __forceinline__ int row_to_seq(int r) {
  int tile = r >> 7, pos = r & 127;
  int ntt = tile >> 4, nth = (tile >> 2) & 3, ntw = tile & 3;
  int tt  = pos >> 6,  th  = (pos >> 3) & 7,  tw  = pos & 7;
  return ((ntt * 2 + tt) << 10) | ((nth * 8 + th) << 5) | (ntw * 8 + tw);
}

// ---------- kernel 1: permute hidden_states rows into tile order (+cast fp32->bf16) ----------
__global__ __launch_bounds__(256) void permute_hs(const float* __restrict__ in,
                                                  unsigned short* __restrict__ out) {
  int cid = blockIdx.x * 256 + threadIdx.x;          // 1,048,576 chunks of 8 elems
  int r = cid >> 7, c = (cid & 127) * 8;
  int s = row_to_seq(r);
  const float* f = in + (size_t)s * 1024 + c;
  u16x8 v;
#pragma unroll
  for (int j = 0; j < 8; ++j) v[j] = f2bf(f[j]);
  *(u16x8*)(out + (size_t)r * 1024 + c) = v;
}

// ---------- kernel 2: transpose the 4 weight matrices [K][N] -> [N][K] (+cast) ----------
__global__ __launch_bounds__(256) void transpose_w(const float* __restrict__ w0,
                                                   const float* __restrict__ w1,
                                                   const float* __restrict__ w2,
                                                   const float* __restrict__ w3,
                                                   unsigned short* __restrict__ out) {
  __shared__ unsigned short Lt[64 * 68];             // [n][k] tile, pad 68
  int m = blockIdx.y;
  const float* W = (m == 0) ? w0 : (m == 1) ? w1 : (m == 2) ? w2 : w3;
  unsigned short* O = out + (size_t)m * 1048576;
  int k0 = (blockIdx.x >> 4) * 64, n0 = (blockIdx.x & 15) * 64;
  int tid = threadIdx.x;
#pragma unroll
  for (int i = 0; i < 2; ++i) {
    int cid = i * 256 + tid;
    int kr = cid >> 3, c = cid & 7;
    const float* f = W + (size_t)(k0 + kr) * 1024 + n0 + c * 8;
#pragma unroll
    for (int j = 0; j < 8; ++j) Lt[(c * 8 + j) * 68 + kr] = f2bf(f[j]);
  }
  __syncthreads();
#pragma unroll
  for (int i = 0; i < 2; ++i) {
    int cid = i * 256 + tid;
    int nr = cid >> 3, c = cid & 7;
    u16x8 v;
#pragma unroll
    for (int j = 0; j < 8; ++j) v[j] = Lt[nr * 68 + c * 8 + j];
    *(u16x8*)(O + (size_t)(n0 + nr) * 1024 + k0 + c * 8) = v;
  }
}

// ---------- gemm_bt: C[M][1024] = (A[M][1024] * Bt[1024][1024]^T) * scale ----------
template <int SCATTER, int OUT_F32>
__device__ __forceinline__ void gemm_bt_body(const unsigned short* __restrict__ A,
                                             const unsigned short* __restrict__ Bt,
                                             void* __restrict__ Cv,
                                             int row0, int col0, float scale) {
  __shared__ unsigned short As[128 * 64];
  __shared__ unsigned short Bs[128 * 64];
  const int tid  = threadIdx.x;
  const int lane = tid & 63, w = tid >> 6;
  const int quad = lane >> 4, lm = lane & 15;
  const int wr = (w >> 1) * 64, wc = (w & 1) * 64;
  f32x4 acc[4][4] = {};
  for (int kt = 0; kt < 16; ++kt) {
    const int k0 = kt * 64;
    __syncthreads();
#pragma unroll
    for (int i = 0; i < 4; ++i) {
      int cid = i * 256 + tid;
      int r = cid >> 3, c = cid & 7;
      int cg = c ^ (r & 7);                          // swizzle on SOURCE address
      int base = (i * 256 + (tid & 192)) * 8;        // wave-uniform LDS dst (u16)
      GLOAD_LDS16(A  + (size_t)(row0 + r) * 1024 + k0 + cg * 8, As + base);
      GLOAD_LDS16(Bt + (size_t)(col0 + r) * 1024 + k0 + cg * 8, Bs + base);
    }
    __syncthreads();
#pragma unroll
    for (int kh = 0; kh < 2; ++kh) {
      short8 af[4], bf[4];
#pragma unroll
      for (int t = 0; t < 4; ++t) {
        int ca = (kh * 4 + quad) ^ (lm & 7);
        af[t] = *(const short8*)(As + (wr + t * 16 + lm) * 64 + ca * 8);
        bf[t] = *(const short8*)(Bs + (wc + t * 16 + lm) * 64 + ca * 8);
      }
#pragma unroll
      for (int rt = 0; rt < 4; ++rt)
#pragma unroll
        for (int ct = 0; ct < 4; ++ct)
          acc[rt][ct] = MFMA_BF16(af[rt], bf[ct], acc[rt][ct]);
    }
  }
#pragma unroll
  for (int rt = 0; rt < 4; ++rt)
#pragma unroll
    for (int ct = 0; ct < 4; ++ct)
#pragma unroll
      for (int g = 0; g < 4; ++g) {
        int R  = row0 + wr + rt * 16 + quad * 4 + g;
        int Cc = col0 + wc + ct * 16 + lm;
        int Rs = SCATTER ? row_to_seq(R) : R;
        float vv = acc[rt][ct][g] * scale;
        if (OUT_F32) ((float*)Cv)[(size_t)Rs * 1024 + Cc] = vv;
        else ((unsigned short*)Cv)[(size_t)Rs * 1024 + Cc] = f2bf(vv);
      }
}

// ---------- gemm_qkv3: the 3 QKV GEMMs fused, SHARED A-staging (r8) ----------
// Round-13: V's transpose is FUSED into the epilogue. Block (x,y) computes
// exactly one [64 d][128 seq] tile of Vt (col0 = x*64 is head-aligned), so
// after the K-loop the dead 40 KB staging pool is reused as a [64][136]
// transpose tile (transpose_v's verified phase-2 code) and V goes straight
// to Vt[16][64][8192]. Kills the transpose_v dispatch AND V's extra HBM
// round-trip (write Vb + read Vb). Q/K stores unchanged.
__global__ __launch_bounds__(256) void gemm_qkv3(const unsigned short* __restrict__ A,
                                                 const unsigned short* __restrict__ Wt,
                                                 unsigned short* __restrict__ QKV,
                                                 unsigned short* __restrict__ Vt) {
  __shared__ unsigned short pool[128 * 64 + 3 * 64 * 64];  // As | Bs0 | Bs1 | Bs2 (40 KB)
  unsigned short* const As = pool;
  const int tid  = threadIdx.x;
  const int lane = tid & 63, w = tid >> 6;
  const int quad = lane >> 4, lm = lane & 15;
  const int wr = (w >> 1) * 64, wc = (w & 1) * 32;   // wave tile 64x32
  const int row0 = blockIdx.y * 128, col0 = blockIdx.x * 64;
  f32x4 acc[3][4][2] = {};
  for (int kt = 0; kt < 16; ++kt) {
    const int k0 = kt * 64;
    __syncthreads();
#pragma unroll
    for (int i = 0; i < 4; ++i) {                    // stage A (4 passes)
      int cid = i * 256 + tid;
      int r = cid >> 3, c = cid & 7;
      int cg = c ^ (r & 7);
      int base = (i * 256 + (tid & 192)) * 8;
      GLOAD_LDS16(A + (size_t)(row0 + r) * 1024 + k0 + cg * 8, As + base);
    }
#pragma unroll
    for (int m = 0; m < 3; ++m)                      // stage 3 B tiles (2 passes each)
#pragma unroll
      for (int i = 0; i < 2; ++i) {
        int cid = i * 256 + tid;
        int r = cid >> 3, c = cid & 7;
        int cg = c ^ (r & 7);
        int base = (i * 256 + (tid & 192)) * 8;
        GLOAD_LDS16(Wt + (size_t)m * 1048576 + (size_t)(col0 + r) * 1024 + k0 + cg * 8,
                    pool + 8192 + m * 4096 + base);
      }
    __syncthreads();
#pragma unroll
    for (int kh = 0; kh < 2; ++kh) {
      const int ca = (kh * 4 + quad) ^ (lm & 7);
      short8 af[4], bf[3][2];
#pragma unroll
      for (int t = 0; t < 4; ++t)
        af[t] = *(const short8*)(As + (wr + t * 16 + lm) * 64 + ca * 8);
#pragma unroll
      for (int m = 0; m < 3; ++m)
#pragma unroll
        for (int u = 0; u < 2; ++u)
          bf[m][u] = *(const short8*)(pool + 8192 + m * 4096 + (wc + u * 16 + lm) * 64 + ca * 8);
#pragma unroll
      for (int m = 0; m < 3; ++m)
#pragma unroll
        for (int t = 0; t < 4; ++t)
#pragma unroll
          for (int u = 0; u < 2; ++u)
            acc[m][t][u] = MFMA_BF16(af[t], bf[m][u], acc[m][t][u]);
    }
  }
  // ---- epilogue: Q (scaled) and K direct; V via LDS transpose ----
#pragma unroll
  for (int m = 0; m < 2; ++m) {
    // fold softmax scale (1/8)*log2(e) into Q so attn's exp2 needs no multiply
    const float scale = (m == 0) ? 0.18033688011112042f : 1.0f;
    unsigned short* Cm = QKV + (size_t)m * 8388608;
#pragma unroll
    for (int t = 0; t < 4; ++t)
#pragma unroll
      for (int u = 0; u < 2; ++u)
#pragma unroll
        for (int g = 0; g < 4; ++g) {
          int R  = row0 + wr + t * 16 + quad * 4 + g;
          int Cc = col0 + wc + u * 16 + lm;
          Cm[(size_t)R * 1024 + Cc] = f2bf(acc[m][t][u][g] * scale);
        }
  }
  __syncthreads();                                   // all LDS reads of As/Bs done
  unsigned short* const Lt = pool;                   // reuse pool: [64 d][136] (17.4 KB)
#pragma unroll
  for (int t = 0; t < 4; ++t)
#pragma unroll
    for (int u = 0; u < 2; ++u)
#pragma unroll
      for (int g = 0; g < 4; ++g) {
        int sl = wr + t * 16 + quad * 4 + g;         // seq-local 0..127
        int d  = wc + u * 16 + lm;                   // 0..63
        Lt[d * 136 + sl] = f2bf(acc[2][t][u][g]);
      }
  __syncthreads();
#pragma unroll
  for (int i = 0; i < 4; ++i) {                      // coalesced Vt store (1024 chunks)
    int cid = i * 256 + tid;
    int d = cid >> 4, c = cid & 15;
    u16x8 v = *(const u16x8*)(Lt + d * 136 + c * 8);
    *(u16x8*)(Vt + (size_t)(blockIdx.x * 64 + d) * 8192 + row0 + c * 8) = v;
  }
}

__global__ __launch_bounds__(256) void gemm_out(const unsigned short* __restrict__ A,
                                                const unsigned short* __restrict__ Wt,
                                                float* __restrict__ Cout) {
  gemm_bt_body<1, 1>(A, Wt, Cout, blockIdx.y * 128, blockIdx.x * 128, 1.0f);
}

// ---------- attention: one block per (head, q-tile), 512 threads (8 waves) ----------
// (byte-identical to round 10, the verified best: 79.9 us, MfmaUtil 31 /
// VALUBusy 30, LDS-BW-bound. r11/r12's paired 32x32 rewrite raced — reverted.)
// 16x16 MFMA, 48 KB LDS, 3 blocks/CU, 2 barriers/iter, V[it]-at-top /
// K[it+1]-after-mid pipelining, precomputed staging offsets, cvt_pk P-pack,
// raw v_exp_f32. (512,4): allocator settles <=64 VGPR; bigger sets spill 10x.
__global__ __launch_bounds__(512, 4) void attn(const unsigned short* __restrict__ Q,
                                               const unsigned short* __restrict__ K,
                                               const unsigned short* __restrict__ Vt,
                                               unsigned short* __restrict__ O) {
  __shared__ unsigned short Ks[128 * 64];            // 16 KB [kv][d], swizzled
  __shared__ unsigned short Vs[64 * 128];            // 16 KB [d][kv], swizzled
  __shared__ unsigned short Pb[8 * 16 * 64];         // 16 KB: per-wave 2 KB P slice

  const int tid  = threadIdx.x;
  const int lane = tid & 63, w = tid >> 6;           // w in 0..7
  const int quad = lane >> 4, lm = lane & 15;
  unsigned short* Pbw = Pb + w * 1024;               // wave-private [q 16][kv 64]

  const int h = blockIdx.x >> 6, qt = blockIdx.x & 63;
  const int ntt = qt >> 4, nth = (qt >> 2) & 3, ntw = qt & 3;
  const int kt0 = min(max(ntt, 1), 2) - 1;           // t-window start tile
  const int kh0 = min(max(nth, 1), 3) - 1;
  const int kw0 = min(max(ntw, 1), 3) - 1;

  // per-lane invariant staging offsets (u32 element offsets)
  const int cid1 = 512 + tid;
  const int rK0 = tid  >> 3, cgK0 = (tid  & 7) ^ (rK0 & 7);
  const int rK1 = cid1 >> 3, cgK1 = (cid1 & 7) ^ (rK1 & 7);
  const unsigned koff0 = rK0 * 1024 + h * 64 + cgK0 * 8;
  const unsigned koff1 = rK1 * 1024 + h * 64 + cgK1 * 8;
  const int dV0 = tid  >> 4, cgV0 = (tid  & 15) ^ (dV0 & 7);
  const int dV1 = cid1 >> 4, cgV1 = (cid1 & 15) ^ (dV1 & 7);
  const unsigned voff0 = (h * 64 + dV0) * 8192 + cgV0 * 8;
  const unsigned voff1 = (h * 64 + dV1) * 8192 + cgV1 * 8;
  const unsigned ldsD0 = (tid & 448) * 8;            // wave-uniform LDS dst (u16)
  const unsigned ldsD1 = (512 + (tid & 448)) * 8;

  // Q B-frags (Q pre-scaled by CSC): n=q = w*16+lm, k=d = kh*32+quad*8+j
  short8 bq[2];
#pragma unroll
  for (int kh = 0; kh < 2; ++kh)
    bq[kh] = *(const short8*)(Q + (size_t)(qt * 128 + w * 16 + lm) * 1024
                                + h * 64 + kh * 32 + quad * 8);

  short8 ones8;
#pragma unroll
  for (int j = 0; j < 8; ++j) ones8[j] = (short)0x3F80;   // bf16 1.0

  f32x4 o_acc[4] = {};                               // [d-tile]
  f32x4 l_acc = {};                                  // row sums of P

  // ---- prologue: stage K tile 0, drain, barrier ----
  {
    const unsigned k0 = (unsigned)(kt0 * 16 + kh0 * 4 + kw0) << 17;
    GLOAD_LDS16(K + koff0 + k0, Ks + ldsD0);
    GLOAD_LDS16(K + koff1 + k0, Ks + ldsD1);
  }
  __syncthreads();                                   // K[0] landed

  for (int it = 0; it < 12; ++it) {
    const int tt2 = it >> 2, hh2 = (it >> 1) & 1, ww2 = it & 1;
    const int kvt = (kt0 + tt2) * 16 + (kh0 + hh2) * 4 + (kw0 + ww2);

    // issue V[it] (latency hidden under QK^T + exp2)
    {
      const unsigned v0 = (unsigned)kvt << 7;
      GLOAD_LDS16(Vt + voff0 + v0, Vs + ldsD0);
      GLOAD_LDS16(Vt + voff1 + v0, Vs + ldsD1);
    }

    // S^T[kv 128][q 16(wave)] = K * Q^T
    f32x4 sa[8] = {};                                // [kv-tile rt]
#pragma unroll
    for (int kh = 0; kh < 2; ++kh) {
      short8 ak[8];
#pragma unroll
      for (int rt = 0; rt < 8; ++rt)
        ak[rt] = *(const short8*)(Ks + (rt * 16 + lm) * 64 + (((kh * 4 + quad) ^ (lm & 7)) * 8));
      __builtin_amdgcn_s_setprio(1);
#pragma unroll
      for (int rt = 0; rt < 8; ++rt)
        sa[rt] = MFMA_BF16(ak[rt], bq[kh], sa[rt]);
      __builtin_amdgcn_s_setprio(0);
    }

    // P = exp2(S^T) packed to bf16 pairs, kept in registers across the barrier
    u32x2 pk[8];
#pragma unroll
    for (int rt = 0; rt < 8; ++rt) {
      pk[rt][0] = pack2bf(exp2_hw(sa[rt][0]), exp2_hw(sa[rt][1]));
      pk[rt][1] = pack2bf(exp2_hw(sa[rt][2]), exp2_hw(sa[rt][3]));
    }

    __syncthreads();   // drains vmcnt -> V[it] landed; all waves done reading Ks

    // prefetch K[it+1] into Ks (latency hidden under PV)
    if (it < 11) {
      const int jt = it + 1;
      const int t2 = jt >> 2, h2 = (jt >> 1) & 1, w2 = jt & 1;
      const unsigned kn = (unsigned)((kt0 + t2) * 16 + (kh0 + h2) * 4 + (kw0 + w2)) << 17;
      GLOAD_LDS16(K + koff0 + kn, Ks + ldsD0);
      GLOAD_LDS16(K + koff1 + kn, Ks + ldsD1);
    }

    // O += P * V ; l += P * 1  — two kv-halves through the 2 KB Pb slice.
    // Same-wave LDS ops are processed in order, so half-1 writes cannot pass
    // half-0 reads; Pbw is wave-private so no barrier is needed.
#pragma unroll
    for (int half = 0; half < 2; ++half) {
#pragma unroll
      for (int rt4 = 0; rt4 < 4; ++rt4) {
        // kv offset rt4*16+quad*4 -> chunk 2rt4+(quad>>1), 8B half quad&1, chunk ^= lm&7
        *(u32x2*)(Pbw + lm * 64 + (((rt4 * 2 + (quad >> 1)) ^ (lm & 7)) * 8) + (quad & 1) * 4)
            = pk[half * 4 + rt4];
      }
#pragma unroll
      for (int ks2 = 0; ks2 < 2; ++ks2) {
        short8 ap = *(const short8*)(Pbw + lm * 64 + (((ks2 * 4 + quad) ^ (lm & 7)) * 8));
        const int ks = half * 2 + ks2;
        short8 bv[4];
#pragma unroll
        for (int nt = 0; nt < 4; ++nt)
          bv[nt] = *(const short8*)(Vs + (nt * 16 + lm) * 128 + (((ks * 4 + quad) ^ (lm & 7)) * 8));
        __builtin_amdgcn_s_setprio(1);
        l_acc = MFMA_BF16(ap, ones8, l_acc);
#pragma unroll
        for (int nt = 0; nt < 4; ++nt)
          o_acc[nt] = MFMA_BF16(ap, bv[nt], o_acc[nt]);
        __builtin_amdgcn_s_setprio(0);
      }
    }

    __syncthreads();   // drains vmcnt -> K[it+1] landed; all waves done reading Vs
  }

  // normalize by l and store (rows q = quad*4+g -> per-lane l)
#pragma unroll
  for (int g = 0; g < 4; ++g) {
    float inv = 1.0f / l_acc[g];
#pragma unroll
    for (int nt = 0; nt < 4; ++nt) {
      int R = qt * 128 + w * 16 + quad * 4 + g;
      O[(size_t)R * 1024 + h * 64 + nt * 16 + lm] = f2bf(o_acc[nt][g] * inv);
    }
  }
}

// ---------- host ----------
extern "C" void kernel_launch(void* const* d_in, const int* in_sizes, int n_in,
                              void* d_out, int out_size, void* d_ws, size_t ws_size,
                              hipStream_t stream) {
  const float* hs = (const float*)d_in[0];
  const float* wq = (const float*)d_in[1];
  const float* wk = (const float*)d_in[2];
  const float* wv = (const float*)d_in[3];
  const float* wo = (const float*)d_in[4];
  float* out = (float*)d_out;                        // reference output dtype = float32

  const size_t NEL = 8388608;                        // 8192*1024
  unsigned short* ws  = (unsigned short*)d_ws;
  unsigned short* HSt = ws;                          // [8192][1024] tile-ordered
  unsigned short* Qb  = ws + 1 * NEL;
  unsigned short* Kb  = ws + 2 * NEL;
  unsigned short* Vb  = ws + 3 * NEL;                // (unused since r13: V goes straight to Vtb)
  unsigned short* Vtb = ws + 4 * NEL;                // [16][64][8192]
  unsigned short* Ot  = ws + 5 * NEL;
  unsigned short* Wt  = ws + 6 * NEL;                // 4 x [1024][1024] transposed
  if (ws_size < (6 * NEL + 4 * 1048576) * sizeof(unsigned short)) return;
  (void)Vb;

  permute_hs<<<4096, 256, 0, stream>>>(hs, HSt);
  transpose_w<<<dim3(256, 4), 256, 0, stream>>>(wq, wk, wv, wo, Wt);
  gemm_qkv3<<<dim3(16, 64), 256, 0, stream>>>(HSt, Wt, Qb, Vtb);  // V transposed in-epilogue
  attn<<<1024, 512, 0, stream>>>(Qb, Kb, Vtb, Ot);
  gemm_out<<<dim3(8, 64, 1), 256, 0, stream>>>(Ot, Wt + 3 * 1048576, out);
  (void)in_sizes; (void)n_in; (void)out_size;
}